// Round 10
// baseline (45.316 us; speedup 1.0000x reference)
//
#include <hip/hip_runtime.h>
#include <hip/hip_bf16.h>
#include <stdint.h>

// Problem constants
#define B_SZ   4096
#define IN_SZ  256
#define U_SZ   128
#define G_SZ   1000
#define LW_SZ  64
#define LB_SZ  32
#define K_SZ   (LW_SZ * IN_SZ)      // 16384

// out[B,U] = A[B,K] * Wf[K,U];  A[b, l*256+i] = zw[b,l] * x[b,i]
// BM=256 8-wave LDS-staged GEMM: B slab read ONCE per block (no register-level
// duplication) -> total operand traffic ~128 MB vs R6's ~340 MB.
#define BM     256
#define BK     64
#define KSPL   16                   // l-split: 4 l's per block
#define NSTEP  16                   // s = c*4 + li (li inner)
#define NTILE  (K_SZ / BK)          // 256 wfT k-tiles
#define BCHUNK 8192                 // shorts per wfT tile (64k x 128u), 16 KB
#define ACHUNK 16384                // shorts per xh chunk (256r x 64k), 32 KB

typedef __attribute__((ext_vector_type(8))) short  bf16x8;
typedef __attribute__((ext_vector_type(4))) float  f32x4;
typedef __attribute__((ext_vector_type(8))) _Float16 f16x8;
typedef __attribute__((ext_vector_type(2))) _Float16 f16x2;

typedef const void __attribute__((address_space(1)))* gas_ptr;
typedef void __attribute__((address_space(3)))* las_ptr;

__device__ __forceinline__ ushort f2bf(float f) {
    unsigned u = __float_as_uint(f);
    u += 0x7fffu + ((u >> 16) & 1u);
    return (ushort)(u >> 16);
}

__device__ __forceinline__ float softplus_f(float v) {
    return fmaxf(v, 0.0f) + log1pf(__expf(-fabsf(v)));
}

__device__ __forceinline__ f16x8 mulzw(f16x8 a, f16x2 z) {
    union { f16x8 v8; f16x2 v2[4]; } in, out;
    in.v8 = a;
    #pragma unroll
    for (int w = 0; w < 4; ++w) out.v2[w] = in.v2[w] * z;   // v_pk_mul_f16
    return out.v8;
}

// ---------------------------------------------------------------------------
// Prep (384 blocks):
//  [0,256):  Wf -> wfT f16 tiles, Bs[u][k] layout, XOR swizzle pre-applied,
//            XCD remap t = ((bid&15)<<4)|(bid>>4) (producer XCD == consumer).
//  [256,384): x -> xh f16, 64 chunks of 256r x 64k (As[r][k] swizzled),
//            2 blocks per chunk (h = row half).
// ---------------------------------------------------------------------------
__global__ __launch_bounds__(256) void fmd_prep(
    const float* __restrict__ Wf, const float* __restrict__ x,
    short* __restrict__ wfT, short* __restrict__ xh)
{
    const int tid = threadIdx.x;
    if (blockIdx.x < NTILE) {
        const int bid = blockIdx.x;
        const int t = ((bid & 15) << 4) | (bid >> 4);   // XCD-aligned remap
        __shared__ float lds[64 * 133];         // [kk][u], pad 133
        #pragma unroll
        for (int it = 0; it < 8; ++it) {
            int idx = it * 256 + tid;           // 2048 float4 slots
            int kk = idx >> 5, u4 = idx & 31;
            float4 v = *reinterpret_cast<const float4*>(&Wf[(t * 64 + kk) * U_SZ + u4 * 4]);
            *reinterpret_cast<float4*>(&lds[kk * 133 + u4 * 4]) = v;
        }
        __syncthreads();
        short* tile = wfT + t * BCHUNK;
        #pragma unroll
        for (int g = 0; g < 4; ++g) {
            int p = g * 2048 + tid * 8;         // short pos, 8-aligned
            int u = p >> 6;
            int cc = p & 63;
            int kk0 = cc ^ ((u & 7) << 3);      // swizzle bits 3..5; cc 8-aligned
            union { _Float16 h[8]; f16x8 v; } pk;
            #pragma unroll
            for (int j = 0; j < 8; ++j)
                pk.h[j] = (_Float16)lds[(kk0 + j) * 133 + u];
            *reinterpret_cast<f16x8*>(&tile[p]) = pk.v;
        }
    } else {
        const int e  = blockIdx.x - NTILE;      // 0..127
        const int bb = e >> 1, h = e & 1;       // chunk, row-half
        const int mt = bb >> 2, c = bb & 3;
        short* chunk = xh + bb * ACHUNK;
        #pragma unroll
        for (int it = 0; it < 4; ++it) {
            int q = h * 1024 + it * 256 + tid;  // f16x8 slot in chunk
            int r  = q >> 3;                    // row 0..255
            int c0 = (q & 7) * 8;
            int cc0 = c0 ^ ((r & 7) << 3);
            const float* src = &x[(mt * BM + r) * IN_SZ + c * 64 + cc0];
            float4 a = *reinterpret_cast<const float4*>(src);
            float4 b = *reinterpret_cast<const float4*>(src + 4);
            union { _Float16 hh[8]; f16x8 v; } pk;
            pk.hh[0] = (_Float16)a.x; pk.hh[1] = (_Float16)a.y;
            pk.hh[2] = (_Float16)a.z; pk.hh[3] = (_Float16)a.w;
            pk.hh[4] = (_Float16)b.x; pk.hh[5] = (_Float16)b.y;
            pk.hh[6] = (_Float16)b.z; pk.hh[7] = (_Float16)b.w;
            *reinterpret_cast<f16x8*>(&chunk[q * 8]) = pk.v;
        }
    }
}

// ---------------------------------------------------------------------------
// GEMM v8: 256 blocks (16 mt x 16 ks), 512 threads = 8 waves (4 wr x 2 wc),
// wave tile 64x64. Both operands LDS-staged via global_load_lds (dbuf),
// zw applied per-li via pk_mul on A fragments. 1 block/CU, 96 KB LDS.
// ---------------------------------------------------------------------------
__global__ __launch_bounds__(512, 1) void fmd_gemm8(
    const short* __restrict__ xh,
    const short* __restrict__ wfT,
    const float* __restrict__ zw_mu,
    const float* __restrict__ zw_sigma,
    const float* __restrict__ eps_w,
    const int*   __restrict__ gid,
    _Float16*    __restrict__ part)
{
    const int tid  = threadIdx.x;
    const int lane = tid & 63;
    const int wid  = tid >> 6;
    const int wr   = wid >> 1;          // 0..3
    const int wc   = wid & 1;           // 0..1
    const int bid  = blockIdx.x;
    const int ks   = bid & (KSPL - 1);
    const int mt   = bid >> 4;
    const int m0   = mt * BM;

    __shared__ short As[2][ACHUNK];     // 64 KB, x (unscaled), swizzled
    __shared__ short Bs[2][BCHUNK];     // 32 KB, Wf^T, swizzled

    // --- per-lane packed zw for its 4 rows x 4 li ---
    f16x2 zwp[4][4];
    #pragma unroll
    for (int m = 0; m < 4; ++m) {
        int row = wr * 64 + m * 16 + (lane & 15);
        int b   = m0 + row;
        int g   = gid[b];
        float4 mu = *reinterpret_cast<const float4*>(&zw_mu[g * LW_SZ + ks * 4]);
        float4 sg = *reinterpret_cast<const float4*>(&zw_sigma[g * LW_SZ + ks * 4]);
        float4 ep = *reinterpret_cast<const float4*>(&eps_w[b * LW_SZ + ks * 4]);
        _Float16 h0 = (_Float16)(mu.x + softplus_f(sg.x) * ep.x);
        _Float16 h1 = (_Float16)(mu.y + softplus_f(sg.y) * ep.y);
        _Float16 h2 = (_Float16)(mu.z + softplus_f(sg.z) * ep.z);
        _Float16 h3 = (_Float16)(mu.w + softplus_f(sg.w) * ep.w);
        zwp[m][0] = (f16x2){h0, h0};
        zwp[m][1] = (f16x2){h1, h1};
        zwp[m][2] = (f16x2){h2, h2};
        zwp[m][3] = (f16x2){h3, h3};
    }

    const int so = tid * 8;             // staging offset (shorts, 16B/thread)

    // prologue: stage B(s=0) -> Bs[0], A(c=0) -> As[0]
    {
        const short* sB = wfT + ((ks * 4 + 0) * 4 + 0) * BCHUNK;
        #pragma unroll
        for (int j = 0; j < 2; ++j)
            __builtin_amdgcn_global_load_lds((gas_ptr)(sB + j * 4096 + so),
                                             (las_ptr)(&Bs[0][j * 4096 + so]), 16, 0, 0);
        const short* sA = xh + (mt * 4 + 0) * ACHUNK;
        #pragma unroll
        for (int j = 0; j < 4; ++j)
            __builtin_amdgcn_global_load_lds((gas_ptr)(sA + j * 4096 + so),
                                             (las_ptr)(&As[0][j * 4096 + so]), 16, 0, 0);
    }
    __syncthreads();   // drains vmcnt: B0/A0 landed

    f32x4 acc[4][4];
    #pragma unroll
    for (int m = 0; m < 4; ++m)
        #pragma unroll
        for (int n = 0; n < 4; ++n)
            acc[m][n] = (f32x4){0.f, 0.f, 0.f, 0.f};

    #pragma unroll
    for (int s = 0; s < NSTEP; ++s) {
        const int c  = s >> 2;
        const int li = s & 3;

        // --- stage next tiles (land in the other buffer) ---
        if (s + 1 < NSTEP) {
            const int sn = s + 1;
            const short* sB = wfT + ((ks * 4 + (sn & 3)) * 4 + (sn >> 2)) * BCHUNK;
            short* dB = &Bs[sn & 1][0];
            #pragma unroll
            for (int j = 0; j < 2; ++j)
                __builtin_amdgcn_global_load_lds((gas_ptr)(sB + j * 4096 + so),
                                                 (las_ptr)(dB + j * 4096 + so), 16, 0, 0);
        }
        if (li == 2 && c < 3) {
            const short* sA = xh + (mt * 4 + c + 1) * ACHUNK;
            short* dA = &As[(c + 1) & 1][0];
            #pragma unroll
            for (int j = 0; j < 4; ++j)
                __builtin_amdgcn_global_load_lds((gas_ptr)(sA + j * 4096 + so),
                                                 (las_ptr)(dA + j * 4096 + so), 16, 0, 0);
        }
        __builtin_amdgcn_sched_barrier(0);   // keep stage-issue before compute

        // --- compute step s from As[c&1], Bs[s&1] ---
        const short* Ab = As[c & 1];
        const short* Bb = Bs[s & 1];
        __builtin_amdgcn_s_setprio(1);
        #pragma unroll
        for (int kb = 0; kb < 2; ++kb) {
            f16x8 af[4], bfv[4];
            #pragma unroll
            for (int m = 0; m < 4; ++m) {
                int row = wr * 64 + m * 16 + (lane & 15);
                int si = (row * BK + kb * 32 + (lane >> 4) * 8) ^ ((row & 7) << 3);
                af[m] = *reinterpret_cast<const f16x8*>(&Ab[si]);
            }
            #pragma unroll
            for (int n = 0; n < 4; ++n) {
                int rowu = wc * 64 + n * 16 + (lane & 15);
                int si = (rowu * BK + kb * 32 + (lane >> 4) * 8) ^ ((rowu & 7) << 3);
                bfv[n] = *reinterpret_cast<const f16x8*>(&Bb[si]);
            }
            #pragma unroll
            for (int m = 0; m < 4; ++m) {
                f16x8 as_ = mulzw(af[m], zwp[m][li]);
                #pragma unroll
                for (int n = 0; n < 4; ++n)
                    acc[m][n] = __builtin_amdgcn_mfma_f32_16x16x32_f16(
                        as_, bfv[n], acc[m][n], 0, 0, 0);
            }
        }
        __builtin_amdgcn_s_setprio(0);
        __syncthreads();   // drains lgkm (our reads) + vmcnt (next stage landed)
    }

    // --- epilogue: f16 partials, slice ks ---
    _Float16* dst = part + (size_t)ks * (B_SZ * U_SZ);
    #pragma unroll
    for (int m = 0; m < 4; ++m) {
        int row0 = m0 + wr * 64 + m * 16 + ((lane >> 4) << 2);
        #pragma unroll
        for (int n = 0; n < 4; ++n) {
            int col = wc * 64 + n * 16 + (lane & 15);
            #pragma unroll
            for (int j = 0; j < 4; ++j)
                dst[(row0 + j) * U_SZ + col] = (_Float16)acc[m][n][j];
        }
    }
}

// ---------------------------------------------------------------------------
// Reduce + bias: out[b,u] = sum_ks part[ks][b][u] + bias[b,u].
// 8 outputs/thread. Overwrites d_out fully (poison reset).
// ---------------------------------------------------------------------------
__global__ __launch_bounds__(256) void fmd_reduce4(
    const _Float16* __restrict__ part,
    const float* __restrict__ eps_b,
    const float* __restrict__ zb_mu,
    const float* __restrict__ zb_sigma,
    const float* __restrict__ Bf,
    const int*   __restrict__ gid,
    float*       __restrict__ out)
{
    const int tid = threadIdx.x;
    const int bid = blockIdx.x;               // 256 blocks
    const int i8  = bid * 256 + tid;          // 8-elem unit index (65536 total)
    const int r   = tid >> 4;                 // local b row 0..15
    const int u0  = (tid & 15) * 8;           // u start

    __shared__ float zb[16][33];
    {
        int e = tid;
        int rr = e >> 5, cc = e & 31;
        int b2 = bid * 16 + rr;
        int g  = gid[b2];
        zb[rr][cc] = zb_mu[g * LB_SZ + cc]
                   + softplus_f(zb_sigma[g * LB_SZ + cc]) * eps_b[b2 * LB_SZ + cc];
        e += 256; rr = e >> 5; cc = e & 31;
        b2 = bid * 16 + rr;
        g  = gid[b2];
        zb[rr][cc] = zb_mu[g * LB_SZ + cc]
                   + softplus_f(zb_sigma[g * LB_SZ + cc]) * eps_b[b2 * LB_SZ + cc];
    }
    __syncthreads();

    f32x4 a0 = (f32x4){0.f, 0.f, 0.f, 0.f};
    f32x4 a1 = (f32x4){0.f, 0.f, 0.f, 0.f};
    #pragma unroll
    for (int l = 0; l < LB_SZ; ++l) {
        float z = zb[r][l];
        f32x4 b0 = *reinterpret_cast<const f32x4*>(&Bf[l * U_SZ + u0]);
        f32x4 b1 = *reinterpret_cast<const f32x4*>(&Bf[l * U_SZ + u0 + 4]);
        a0 += z * b0;
        a1 += z * b1;
    }

    #pragma unroll
    for (int ks = 0; ks < KSPL; ++ks) {
        f16x8 p = *reinterpret_cast<const f16x8*>(
            &part[(size_t)ks * (B_SZ * U_SZ) + (size_t)i8 * 8]);
        a0[0] += (float)p[0]; a0[1] += (float)p[1];
        a0[2] += (float)p[2]; a0[3] += (float)p[3];
        a1[0] += (float)p[4]; a1[1] += (float)p[5];
        a1[2] += (float)p[6]; a1[3] += (float)p[7];
    }
    *reinterpret_cast<f32x4*>(&out[(size_t)i8 * 8])     = a0;
    *reinterpret_cast<f32x4*>(&out[(size_t)i8 * 8 + 4]) = a1;
}

// ---------------------------------------------------------------------------
// Legacy fallback (no workspace): bias + atomic GEMM (bf16)
// ---------------------------------------------------------------------------
__global__ __launch_bounds__(256) void fmd_bias(
    const float* __restrict__ eps_b,
    const float* __restrict__ zb_mu,
    const float* __restrict__ zb_sigma,
    const float* __restrict__ Bf,
    const int*   __restrict__ gid,
    float*       __restrict__ out)
{
    const int half = threadIdx.x >> 7;
    const int u    = threadIdx.x & 127;
    const int b    = blockIdx.x * 2 + half;

    __shared__ float zb[2][LB_SZ];
    if (u < LB_SZ) {
        int g = gid[b];
        float sg = softplus_f(zb_sigma[g * LB_SZ + u]);
        zb[half][u] = zb_mu[g * LB_SZ + u] + sg * eps_b[b * LB_SZ + u];
    }
    __syncthreads();

    float acc = 0.0f;
    #pragma unroll
    for (int l = 0; l < LB_SZ; ++l)
        acc += zb[half][l] * Bf[l * U_SZ + u];
    out[b * U_SZ + u] = acc;
}

__global__ __launch_bounds__(256, 2) void fmd_gemm_legacy(
    const float* __restrict__ x,
    const float* __restrict__ eps_w,
    const float* __restrict__ zw_mu,
    const float* __restrict__ zw_sigma,
    const float* __restrict__ Wf,
    const int*   __restrict__ gid,
    float*       __restrict__ out)
{
    const int tid  = threadIdx.x;
    const int lane = tid & 63;
    const int wid  = tid >> 6;
    const int wr   = wid >> 1;
    const int wc   = wid & 1;
    const int bid  = blockIdx.x;
    const int ks   = bid & (KSPL - 1);
    const int mt   = bid >> 4;
    const int m0   = mt * 128;

    __shared__ short As[128 * 64];
    __shared__ short Bs[U_SZ * 64];
    __shared__ float zw_s[128][4];

    for (int it = tid; it < 128 * 4; it += 256) {
        int r = it >> 2, lloc = it & 3;
        int b = m0 + r;
        int g = gid[b];
        int l = ks * 4 + lloc;
        float sg = softplus_f(zw_sigma[g * LW_SZ + l]);
        zw_s[r][lloc] = zw_mu[g * LW_SZ + l] + sg * eps_w[b * LW_SZ + l];
    }

    f32x4 acc[4][4];
    #pragma unroll
    for (int m = 0; m < 4; ++m)
        #pragma unroll
        for (int n = 0; n < 4; ++n)
            acc[m][n] = (f32x4){0.f, 0.f, 0.f, 0.f};

    for (int s = 0; s < NSTEP; ++s) {
        __syncthreads();
        const int li = s >> 2;
        const int i0 = (s & 3) * 64;
        const int k0 = ks * (K_SZ / KSPL) + s * 64;

        #pragma unroll
        for (int it = 0; it < 8; ++it) {
            int idx = it * 256 + tid;
            int r = idx >> 4, c4 = idx & 15;
            float4 xv = *reinterpret_cast<const float4*>(&x[(m0 + r) * IN_SZ + i0 + c4 * 4]);
            float zw = zw_s[r][li];
            ushort h0 = f2bf(xv.x * zw), h1 = f2bf(xv.y * zw);
            ushort h2 = f2bf(xv.z * zw), h3 = f2bf(xv.w * zw);
            unsigned long long pw = (unsigned long long)h0
                                  | ((unsigned long long)h1 << 16)
                                  | ((unsigned long long)h2 << 32)
                                  | ((unsigned long long)h3 << 48);
            int si = (r * 64 + c4 * 4) ^ ((r & 7) << 3);
            *reinterpret_cast<unsigned long long*>(&As[si]) = pw;
        }
        #pragma unroll
        for (int it = 0; it < 4; ++it) {
            int idx = it * 256 + tid;
            int u = idx & 127, kg = idx >> 7;
            union { ushort h[8]; bf16x8 v; } pk;
            #pragma unroll
            for (int j = 0; j < 8; ++j)
                pk.h[j] = f2bf(Wf[(k0 + kg * 8 + j) * U_SZ + u]);
            int si = (u * 64 + kg * 8) ^ ((u & 7) << 3);
            *reinterpret_cast<bf16x8*>(&Bs[si]) = pk.v;
        }
        __syncthreads();

        #pragma unroll
        for (int kb = 0; kb < 2; ++kb) {
            bf16x8 af[4], bfr[4];
            #pragma unroll
            for (int m = 0; m < 4; ++m) {
                int row = wr * 64 + m * 16 + (lane & 15);
                int si = (row * 64 + kb * 32 + (lane >> 4) * 8) ^ ((row & 7) << 3);
                af[m] = *reinterpret_cast<const bf16x8*>(&As[si]);
            }
            #pragma unroll
            for (int n = 0; n < 4; ++n) {
                int rowu = wc * 64 + n * 16 + (lane & 15);
                int si = (rowu * 64 + kb * 32 + (lane >> 4) * 8) ^ ((rowu & 7) << 3);
                bfr[n] = *reinterpret_cast<const bf16x8*>(&Bs[si]);
            }
            #pragma unroll
            for (int m = 0; m < 4; ++m)
                #pragma unroll
                for (int n = 0; n < 4; ++n)
                    acc[m][n] = __builtin_amdgcn_mfma_f32_16x16x32_bf16(af[m], bfr[n], acc[m][n], 0, 0, 0);
        }
    }

    #pragma unroll
    for (int m = 0; m < 4; ++m) {
        int row0 = m0 + wr * 64 + m * 16 + ((lane >> 4) << 2);
        #pragma unroll
        for (int n = 0; n < 4; ++n) {
            int col = wc * 64 + n * 16 + (lane & 15);
            #pragma unroll
            for (int j = 0; j < 4; ++j)
                atomicAdd(&out[(row0 + j) * U_SZ + col], acc[m][n][j]);
        }
    }
}

extern "C" void kernel_launch(void* const* d_in, const int* in_sizes, int n_in,
                              void* d_out, int out_size, void* d_ws, size_t ws_size,
                              hipStream_t stream) {
    const float* x        = (const float*)d_in[0];
    const float* eps_w    = (const float*)d_in[1];
    const float* eps_b    = (const float*)d_in[2];
    const float* zw_mu    = (const float*)d_in[3];
    const float* zw_sigma = (const float*)d_in[4];
    const float* Wf       = (const float*)d_in[5];
    const float* zb_mu    = (const float*)d_in[6];
    const float* zb_sigma = (const float*)d_in[7];
    const float* Bf       = (const float*)d_in[8];
    const int*   gid      = (const int*)d_in[9];
    float* out = (float*)d_out;

    const size_t WFT_BYTES  = (size_t)K_SZ * U_SZ * 2;            // 4 MB
    const size_t XH_OFF     = WFT_BYTES;
    const size_t XH_BYTES   = (size_t)B_SZ * IN_SZ * 2;           // 2 MB
    const size_t PART_OFF   = XH_OFF + XH_BYTES;
    const size_t PART_BYTES = (size_t)KSPL * B_SZ * U_SZ * 2;     // 16 MB

    if (ws_size >= PART_OFF + PART_BYTES) {
        short*     wfT  = (short*)d_ws;
        short*     xh   = (short*)((char*)d_ws + XH_OFF);
        _Float16*  part = (_Float16*)((char*)d_ws + PART_OFF);
        fmd_prep<<<NTILE + 128, 256, 0, stream>>>(Wf, x, wfT, xh);
        fmd_gemm8<<<(B_SZ / BM) * KSPL, 512, 0, stream>>>(
            xh, wfT, zw_mu, zw_sigma, eps_w, gid, part);
        fmd_reduce4<<<(B_SZ * U_SZ) / 2048, 256, 0, stream>>>(
            part, eps_b, zb_mu, zb_sigma, Bf, gid, out);
    } else {
        fmd_bias<<<B_SZ / 2, 256, 0, stream>>>(eps_b, zb_mu, zb_sigma, Bf, gid, out);
        fmd_gemm_legacy<<<(B_SZ / 128) * KSPL, 256, 0, stream>>>(
            x, eps_w, zw_mu, zw_sigma, Wf, gid, out);
    }
}